// Round 2
// baseline (3071.020 us; speedup 1.0000x reference)
//
#include <hip/hip_runtime.h>
#include <cstdint>
#include <cstddef>

typedef __bf16 bf16x8 __attribute__((ext_vector_type(8)));
typedef __bf16 bf16x4v __attribute__((ext_vector_type(4)));
typedef float  f32x4  __attribute__((ext_vector_type(4)));

#define MFMA16(a, b, c) __builtin_amdgcn_mfma_f32_16x16x32_bf16((a), (b), (c), 0, 0, 0)

__device__ __forceinline__ float sigm(float x) {
    return 1.f / (1.f + __expf(-x));
}
__device__ __forceinline__ float tanh_(float x) {
    // tanh(x) = 1 - 2/(e^{2x}+1); expf overflow -> inf -> 1/inf=0 -> 1 (graceful)
    return 1.f - 2.f / (__expf(2.f * x) + 1.f);
}

// ---------------------------------------------------------------------------
// Repack the four H-recurrence weight matrices (256x256 fp32, W[k][h]) into
// bf16 MFMA B-fragment order for 16x16x32_bf16:
//   o = ((nt*8 + kb)*64 + lane)*8 + j ;  n = nt*16+(lane&15) = g*256+h ;
//   k = kb*32 + (lane>>4)*8 + j
// ---------------------------------------------------------------------------
__global__ void prep_wh(const float* __restrict__ Wf, const float* __restrict__ Wp,
                        const float* __restrict__ Wt, const float* __restrict__ Wo,
                        __bf16* __restrict__ out) {
    int o  = blockIdx.x * 256 + threadIdx.x;   // 262144 total
    int j  = o & 7;
    int l  = (o >> 3) & 63;
    int kb = (o >> 9) & 7;
    int nt = o >> 12;                          // 0..63
    int n  = nt * 16 + (l & 15);
    int g  = n >> 8, h = n & 255;
    int k  = kb * 32 + (l >> 4) * 8 + j;       // 0..255
    const float* W = (g == 0) ? Wf : (g == 1) ? Wp : (g == 2) ? Wt : Wo;
    out[o] = (__bf16)W[k * 256 + h];
}

// Same for the x-projection weights (128x256), K=128 -> kb 0..3
__global__ void prep_wx(const float* __restrict__ Wf, const float* __restrict__ Wp,
                        const float* __restrict__ Wt, const float* __restrict__ Wo,
                        __bf16* __restrict__ out) {
    int o  = blockIdx.x * 256 + threadIdx.x;   // 131072 total
    int j  = o & 7;
    int l  = (o >> 3) & 63;
    int kb = (o >> 9) & 3;
    int nt = o >> 11;                          // 0..63
    int n  = nt * 16 + (l & 15);
    int g  = n >> 8, h = n & 255;
    int k  = kb * 32 + (l >> 4) * 8 + j;       // 0..127
    const float* W = (g == 0) ? Wf : (g == 1) ? Wp : (g == 2) ? Wt : Wo;
    out[o] = (__bf16)W[k * 256 + h];
}

// ---------------------------------------------------------------------------
// Chunked x-projection GEMM. Chunk c covers time steps [c*Tc, (c+1)*Tc).
// Row r = b*Tc + tc  (b = batch, tc = chunk-local step), M = 256*Tc.
// XP[r][n] = x[b, c*Tc+tc, :]·Wx_g[:, h] + bias_g[h],  n = g*256+h, bf16 out.
// Block tile 128x128, 4 waves, A staged fp32->bf16 via LDS; B fragments read
// straight from the prepacked (L2/L3-resident) global array.
// ---------------------------------------------------------------------------
__global__ __launch_bounds__(256) void xproj_gemm(
        const float* __restrict__ x, const __bf16* __restrict__ wxfrag,
        const float* __restrict__ bf, const float* __restrict__ bp,
        const float* __restrict__ bt, const float* __restrict__ bo,
        __bf16* __restrict__ xp, int Tc, int chunk) {
    __shared__ __align__(16) __bf16 As[128 * 128];   // 32 KB
    const int tid = threadIdx.x;
    const int m0  = blockIdx.x * 128;
    const int by  = blockIdx.y;                      // 0..7 (N-tile of 128)
    const int c0  = chunk * Tc;

    // stage A: 128 chunk-rows x 128 cols, fp32 -> bf16
#pragma unroll
    for (int i = 0; i < 16; i++) {
        int f   = i * 256 + tid;
        int row = f >> 5;
        int c4  = (f & 31) * 4;
        int r   = m0 + row;
        int b   = r / Tc;
        int tc  = r - b * Tc;
        float4 v = *reinterpret_cast<const float4*>(
            x + ((size_t)b * 1024 + (size_t)(c0 + tc)) * 128 + c4);
        bf16x4v w;
        w[0] = (__bf16)v.x; w[1] = (__bf16)v.y; w[2] = (__bf16)v.z; w[3] = (__bf16)v.w;
        *reinterpret_cast<bf16x4v*>(&As[row * 128 + c4]) = w;
    }
    __syncthreads();

    const int wv = tid >> 6, l = tid & 63, lm = l & 15, lk = l >> 4;
    const bf16x8* bfr = reinterpret_cast<const bf16x8*>(wxfrag);

    f32x4 acc[2][8];
#pragma unroll
    for (int a = 0; a < 2; a++)
#pragma unroll
        for (int c = 0; c < 8; c++) acc[a][c] = (f32x4){0.f, 0.f, 0.f, 0.f};

#pragma unroll
    for (int kb = 0; kb < 4; kb++) {
        bf16x8 afr[2];
#pragma unroll
        for (int tr = 0; tr < 2; tr++)
            afr[tr] = *reinterpret_cast<const bf16x8*>(
                &As[(wv * 32 + tr * 16 + lm) * 128 + kb * 32 + lk * 8]);
#pragma unroll
        for (int tc = 0; tc < 8; tc++) {
            int nt = by * 8 + tc;
            bf16x8 bq = bfr[(nt * 4 + kb) * 64 + l];
            acc[0][tc] = MFMA16(afr[0], bq, acc[0][tc]);
            acc[1][tc] = MFMA16(afr[1], bq, acc[1][tc]);
        }
    }

    const int g = by >> 1;
    const float* bias = (g == 0) ? bf : (g == 1) ? bp : (g == 2) ? bt : bo;
#pragma unroll
    for (int tc = 0; tc < 8; tc++) {
        int n = by * 128 + tc * 16 + lm;
        float bv = bias[n & 255];
#pragma unroll
        for (int tr = 0; tr < 2; tr++) {
#pragma unroll
            for (int r = 0; r < 4; r++) {
                int row = m0 + wv * 32 + tr * 16 + lk * 4 + r;
                xp[(size_t)row * 1024 + n] = (__bf16)(acc[tr][tc][r] + bv);
            }
        }
    }
}

// ---------------------------------------------------------------------------
// Persistent recurrence over one time chunk. 256 blocks (1 batch row / CU),
// 256 threads (4 waves, 1/SIMD). Wave g owns gate g's 16 N-tiles: 12 with
// weights resident in VGPRs (384 regs/wave), 4 in LDS (128 KB static).
// M=1-padded MFMA: A = short broadcast to all 16 M-rows; D row 0 is real.
// State (short,long) carried across chunks via fp32 arrays in workspace.
// ---------------------------------------------------------------------------
__global__ __launch_bounds__(256, 1) void recur(
        const __bf16* __restrict__ xp, const __bf16* __restrict__ whfrag,
        float* __restrict__ state_s, float* __restrict__ state_l,
        float* __restrict__ out, int Tc, int first, int last) {
    __shared__ __align__(16) bf16x8 wlds[4 * 4 * 8 * 64];   // 131072 B
    __shared__ float  zbuf[1024];                           //   4096 B
    __shared__ __bf16 sbuf[256];                            //    512 B

    const int tid = threadIdx.x, wv = tid >> 6, l = tid & 63, lk = l >> 4;
    const int b = blockIdx.x;
    const bf16x8* wf = reinterpret_cast<const bf16x8*>(whfrag);

    // register-resident weight fragments: tiles 0..11 of this wave's gate
    bf16x8 wreg[96];
#pragma unroll
    for (int t = 0; t < 12; t++)
#pragma unroll
        for (int kb = 0; kb < 8; kb++)
            wreg[t * 8 + kb] = wf[((wv * 16 + t) * 8 + kb) * 64 + l];
    // LDS-resident weight fragments: tiles 12..15
#pragma unroll
    for (int t = 12; t < 16; t++)
#pragma unroll
        for (int kb = 0; kb < 8; kb++)
            wlds[((wv * 4 + (t - 12)) * 8 + kb) * 64 + l] =
                wf[((wv * 16 + t) * 8 + kb) * 64 + l];

    float shortv, longv;
    if (first) { shortv = 0.f; longv = 0.f; }
    else       { shortv = state_s[(b << 8) + tid]; longv = state_l[(b << 8) + tid]; }
    sbuf[tid] = (__bf16)shortv;
    __syncthreads();

    const size_t rowbase = (size_t)b * (size_t)Tc * 1024;

    for (int t = 0; t < Tc; t++) {
        size_t ro = rowbase + (size_t)t * 1024;
        float xv0 = (float)xp[ro + tid];
        float xv1 = (float)xp[ro + 256 + tid];
        float xv2 = (float)xp[ro + 512 + tid];
        float xv3 = (float)xp[ro + 768 + tid];

        // A-fragments: broadcast the short vector into every M-row
        bf16x8 a[8];
#pragma unroll
        for (int kb = 0; kb < 8; kb++)
            a[kb] = *reinterpret_cast<const bf16x8*>(&sbuf[kb * 32 + lk * 8]);

        // 3 register tile-groups of 4 tiles (4-way accumulator interleave)
#pragma unroll
        for (int tg = 0; tg < 3; tg++) {
            f32x4 ac0 = {0.f, 0.f, 0.f, 0.f}, ac1 = ac0, ac2 = ac0, ac3 = ac0;
#pragma unroll
            for (int kb = 0; kb < 8; kb++) {
                ac0 = MFMA16(a[kb], wreg[(tg * 4 + 0) * 8 + kb], ac0);
                ac1 = MFMA16(a[kb], wreg[(tg * 4 + 1) * 8 + kb], ac1);
                ac2 = MFMA16(a[kb], wreg[(tg * 4 + 2) * 8 + kb], ac2);
                ac3 = MFMA16(a[kb], wreg[(tg * 4 + 3) * 8 + kb], ac3);
            }
            if (l < 16) {
                zbuf[wv * 256 + (tg * 4 + 0) * 16 + l] = ac0[0];
                zbuf[wv * 256 + (tg * 4 + 1) * 16 + l] = ac1[0];
                zbuf[wv * 256 + (tg * 4 + 2) * 16 + l] = ac2[0];
                zbuf[wv * 256 + (tg * 4 + 3) * 16 + l] = ac3[0];
            }
        }
        // LDS tile-group (tiles 12..15)
        {
            f32x4 ac0 = {0.f, 0.f, 0.f, 0.f}, ac1 = ac0, ac2 = ac0, ac3 = ac0;
#pragma unroll
            for (int kb = 0; kb < 8; kb++) {
                ac0 = MFMA16(a[kb], wlds[((wv * 4 + 0) * 8 + kb) * 64 + l], ac0);
                ac1 = MFMA16(a[kb], wlds[((wv * 4 + 1) * 8 + kb) * 64 + l], ac1);
                ac2 = MFMA16(a[kb], wlds[((wv * 4 + 2) * 8 + kb) * 64 + l], ac2);
                ac3 = MFMA16(a[kb], wlds[((wv * 4 + 3) * 8 + kb) * 64 + l], ac3);
            }
            if (l < 16) {
                zbuf[wv * 256 + 12 * 16 + l] = ac0[0];
                zbuf[wv * 256 + 13 * 16 + l] = ac1[0];
                zbuf[wv * 256 + 14 * 16 + l] = ac2[0];
                zbuf[wv * 256 + 15 * 16 + l] = ac3[0];
            }
        }
        __syncthreads();

        // elementwise recurrence: thread tid = hidden unit h, all 4 gates
        float zf = zbuf[tid]       + xv0;
        float zp = zbuf[256 + tid] + xv1;
        float zt = zbuf[512 + tid] + xv2;
        float zo = zbuf[768 + tid] + xv3;
        float fg  = sigm(zf);
        float pg  = sigm(zp);
        float ptg = tanh_(zt);
        float og  = sigm(zo);
        longv  = fg * longv + pg * ptg;
        shortv = tanh_(longv) * og;
        sbuf[tid] = (__bf16)shortv;
        __syncthreads();
    }

    state_s[(b << 8) + tid] = shortv;
    state_l[(b << 8) + tid] = longv;
    if (last) {
        out[(b << 8) + tid]         = shortv;   // short
        out[65536 + (b << 8) + tid] = longv;    // long
    }
}

// ---------------------------------------------------------------------------
extern "C" void kernel_launch(void* const* d_in, const int* in_sizes, int n_in,
                              void* d_out, int out_size, void* d_ws, size_t ws_size,
                              hipStream_t stream) {
    const float* x   = (const float*)d_in[0];
    const float* Wfh = (const float*)d_in[1];
    const float* Wfx = (const float*)d_in[2];
    const float* bf_ = (const float*)d_in[3];
    const float* Wph = (const float*)d_in[4];
    const float* Wpx = (const float*)d_in[5];
    const float* bp_ = (const float*)d_in[6];
    const float* Wth = (const float*)d_in[7];
    const float* Wtx = (const float*)d_in[8];
    const float* bt_ = (const float*)d_in[9];
    const float* Woh = (const float*)d_in[10];
    const float* Wox = (const float*)d_in[11];
    const float* bo_ = (const float*)d_in[12];
    float* out = (float*)d_out;

    const size_t WHB = (size_t)262144 * 2;   // 512 KB prepacked Wh
    const size_t WXB = (size_t)131072 * 2;   // 256 KB prepacked Wx
    const size_t STB = (size_t)65536 * 4;    // 256 KB per state array

    // pick largest time-chunk whose XP buffer fits the workspace
    int Tc = 128;
    while (Tc > 8) {
        size_t need = (size_t)256 * Tc * 1024 * 2 + WHB + WXB + 2 * STB;
        if (need <= ws_size) break;
        Tc >>= 1;
    }

    char* wsb = (char*)d_ws;
    __bf16* xpbuf   = (__bf16*)wsb;
    char*   rest    = wsb + (size_t)256 * Tc * 1024 * 2;
    __bf16* whfrag  = (__bf16*)rest;
    __bf16* wxfrag  = (__bf16*)(rest + WHB);
    float*  state_s = (float*)(rest + WHB + WXB);
    float*  state_l = (float*)(rest + WHB + WXB + STB);

    prep_wh<<<1024, 256, 0, stream>>>(Wfh, Wph, Wth, Woh, whfrag);
    prep_wx<<<512, 256, 0, stream>>>(Wfx, Wpx, Wtx, Wox, wxfrag);

    const int nchunk = 1024 / Tc;
    for (int c = 0; c < nchunk; c++) {
        xproj_gemm<<<dim3(2 * Tc, 8), 256, 0, stream>>>(
            x, wxfrag, bf_, bp_, bt_, bo_, xpbuf, Tc, c);
        recur<<<256, 256, 0, stream>>>(
            xpbuf, whfrag, state_s, state_l, out, Tc,
            (c == 0) ? 1 : 0, (c == nchunk - 1) ? 1 : 0);
    }
}